// Round 1
// 595.883 us; speedup vs baseline: 1.1972x; 1.1972x over previous
//
#include <hip/hip_runtime.h>
#include <hip/hip_bf16.h>
#include <math.h>

typedef unsigned short u16;
typedef __attribute__((ext_vector_type(8))) short bf16x8;
typedef __attribute__((ext_vector_type(8))) unsigned short us8;
typedef __attribute__((ext_vector_type(4))) float f32x4;

static __device__ __forceinline__ u16 f2bf(float f) {
  __hip_bfloat16 h = __float2bfloat16(f);
  return *reinterpret_cast<u16*>(&h);
}

// ---------------------------------------------------------------------------
// K0: x fp32 -> bf16 (288x1024)
// ---------------------------------------------------------------------------
__global__ __launch_bounds__(256) void conv_x(const float* __restrict__ x,
                                              u16* __restrict__ xb) {
  int idx = (blockIdx.x * 256 + threadIdx.x) * 4;
  float4 v = *(const float4*)(x + idx);
  ushort4 o;
  o.x = f2bf(v.x); o.y = f2bf(v.y); o.z = f2bf(v.z); o.w = f2bf(v.w);
  *(ushort4*)(xb + idx) = o;
}

// ---------------------------------------------------------------------------
// K0b: W_proj [1024][150] fp32 -> WT4 [p][160][1024] bf16, pads (j>=150) zero
// ---------------------------------------------------------------------------
__global__ __launch_bounds__(256) void trans_wp(
    const float* __restrict__ W0, const float* __restrict__ W1,
    const float* __restrict__ W2, const float* __restrict__ W3,
    u16* __restrict__ WT4) {
  __shared__ float lds[64 * 151];
  int kt = blockIdx.x, p = blockIdx.y;
  const float* W = (p == 0) ? W0 : (p == 1) ? W1 : (p == 2) ? W2 : W3;
  for (int t = threadIdx.x; t < 64 * 150; t += 256) {
    int k = t / 150, j = t - k * 150;
    lds[k * 151 + j] = W[(size_t)(kt * 64 + k) * 150 + j];
  }
  __syncthreads();
  u16* dst = WT4 + (size_t)p * 160 * 1024 + kt * 64;
  for (int t = threadIdx.x; t < 160 * 64; t += 256) {
    int j = t >> 6, kk = t & 63;
    float v = (j < 150) ? lds[kk * 151 + j] : 0.f;
    dst[(size_t)j * 1024 + kk] = f2bf(v);
  }
}

// ---------------------------------------------------------------------------
// transpose W_tri [600 oi][150 k][150 j] fp32 -> WtT [600][160 j][160 k] bf16
// grid (600, 2): block handles one j-half (80 cols). Vectorized float2 read /
// ushort8 write. LDS 49.2 KB -> 3 blocks/CU.
// ---------------------------------------------------------------------------
__global__ __launch_bounds__(256) void transw_kernel(
    const float* __restrict__ W, u16* __restrict__ WtT) {
  __shared__ float lds[150 * 82];
  int oi = blockIdx.x, jh = blockIdx.y;
  const float* src = W + (size_t)oi * 22500 + jh * 80;
  for (int t = threadIdx.x; t < 150 * 40; t += 256) {
    int k = t / 40, c = t - k * 40;
    if (jh * 80 + 2 * c < 150) {
      float2 v = *(const float2*)(src + (size_t)k * 150 + 2 * c);
      *(float2*)&lds[k * 82 + 2 * c] = v;
    }
  }
  __syncthreads();
  u16* dst = WtT + (size_t)oi * 25600 + (size_t)jh * 80 * 160;
  for (int t = threadIdx.x; t < 80 * 20; t += 256) {
    int jl = t / 20, kc = t - jl * 20;
    int j = jh * 80 + jl;
    bool jlive = (j < 150);
    us8 v;
#pragma unroll
    for (int u = 0; u < 8; ++u) {
      int k = kc * 8 + u;
      float f = (jlive && k < 150) ? lds[k * 82 + jl] : 0.f;
      v[u] = f2bf(f);
    }
    *(us8*)(dst + (size_t)jl * 160 + kc * 8) = v;
  }
}

// ---------------------------------------------------------------------------
// Direct-streaming NT-GEMM: no LDS, no barriers. Block 192 thr = 3 waves,
// block tile M144 x N80, wave tile 48x80 (3x5 frags). A/B MFMA fragments are
// loaded straight from global (each bf16x8 frag-load instr = 16 rows x 64 B
// contiguous = fully-coalesced cache lines; A/B tiles are L1/L2-resident).
// STAGE 0 (proj): K=1024. grid (8 ntile over 640, 2 mtile over 288).
//   A=xb, B=WT4, C=pAll [p][288][160] + bias, pads j>=150 -> 0.
// STAGE 1: K=160. grid (2 ntile, 600 oi, 2 b).
//   A=sh(z0), B=WtT[oi], C=wbuf[b][z][o][i][j].
// STAGE 2: K=160. grid (2 ntile, Zcur*4 f2, 2 b).
//   A=pQ, B=wbuf[b][f2], C=tbuf[b][f2][q][i].
// ---------------------------------------------------------------------------
template <int STAGE>
__global__ __launch_bounds__(192) void gemm_ds(
    const u16* __restrict__ A, const u16* __restrict__ B, u16* __restrict__ C,
    int Mvalid, int ZcapW, int ZcapT, const float* __restrict__ bias0,
    const float* __restrict__ bias1, const float* __restrict__ bias2,
    const float* __restrict__ bias3) {
  constexpr int KS = (STAGE == 0) ? 32 : 5;      // K/32
  constexpr int AS = (STAGE == 0) ? 1024 : 160;  // row stride (u16)
  const u16 *Ab, *Bb;
  u16* Cb = nullptr;
  int cstride = 0;
  int mrow0 = 0;
  if (STAGE == 0) {
    mrow0 = blockIdx.y * 144;
    Ab = A + (size_t)mrow0 * 1024;
    Bb = B + (size_t)blockIdx.x * 80 * 1024;
  } else if (STAGE == 1) {
    int ntile = blockIdx.x, oi = blockIdx.y, b = blockIdx.z;
    int o = oi / 150, i = oi - o * 150;
    Ab = A + (size_t)b * 23040;
    Bb = B + (size_t)oi * 25600 + ntile * 12800;
    Cb = C + (size_t)b * ZcapW + ((size_t)o * 160 + i) * 160 + ntile * 80;
    cstride = 102400;
  } else {
    int ntile = blockIdx.x, f2 = blockIdx.y, b = blockIdx.z;
    Ab = A + (size_t)b * 23040;
    Bb = B + (size_t)b * ZcapW + (size_t)f2 * 25600 + ntile * 12800;
    Cb = C + (size_t)b * ZcapT + (size_t)f2 * 23040 + ntile * 80;
    cstride = 160;
  }
  int tid = threadIdx.x;
  int lane = tid & 63, wave = tid >> 6;
  int l16 = lane & 15, quad = lane >> 4;
  const u16* Ap = Ab + (size_t)(wave * 48 + l16) * AS + quad * 8;
  const u16* Bp = Bb + (size_t)l16 * AS + quad * 8;
  f32x4 acc[3][5];
#pragma unroll
  for (int mi = 0; mi < 3; ++mi)
#pragma unroll
    for (int ni = 0; ni < 5; ++ni) acc[mi][ni] = (f32x4){0.f, 0.f, 0.f, 0.f};

#pragma unroll
  for (int ks = 0; ks < KS; ++ks) {
    bf16x8 af[3], bfr[5];
#pragma unroll
    for (int mi = 0; mi < 3; ++mi)
      af[mi] = *(const bf16x8*)(Ap + (size_t)mi * 16 * AS + ks * 32);
#pragma unroll
    for (int ni = 0; ni < 5; ++ni)
      bfr[ni] = *(const bf16x8*)(Bp + (size_t)ni * 16 * AS + ks * 32);
#pragma unroll
    for (int mi = 0; mi < 3; ++mi)
#pragma unroll
      for (int ni = 0; ni < 5; ++ni)
        acc[mi][ni] = __builtin_amdgcn_mfma_f32_16x16x32_bf16(
            af[mi], bfr[ni], acc[mi][ni], 0, 0, 0);
  }

  if (STAGE == 0) {
    int nbase = blockIdx.x * 80;
#pragma unroll
    for (int ni = 0; ni < 5; ++ni) {
      int n = nbase + ni * 16 + l16;
      int p = n / 160, j = n - p * 160;
      const float* bp =
          (p == 0) ? bias0 : (p == 1) ? bias1 : (p == 2) ? bias2 : bias3;
      bool live = (j < 150);
      float bv = live ? bp[j] : 0.f;
#pragma unroll
      for (int mi = 0; mi < 3; ++mi) {
        int row = mrow0 + wave * 48 + mi * 16 + quad * 4;
#pragma unroll
        for (int r = 0; r < 4; ++r) {
          float v = live ? acc[mi][ni][r] + bv : 0.f;
          C[((size_t)p * 288 + row + r) * 160 + j] = f2bf(v);
        }
      }
    }
  } else {
#pragma unroll
    for (int mi = 0; mi < 3; ++mi) {
      int grow0 = wave * 48 + mi * 16 + quad * 4;
#pragma unroll
      for (int ni = 0; ni < 5; ++ni)
#pragma unroll
        for (int r = 0; r < 4; ++r) {
          int grow = grow0 + r;
          if (grow < Mvalid)
            Cb[(size_t)grow * cstride + ni * 16 + l16] = f2bf(acc[mi][ni][r]);
        }
    }
  }
}

// ---------------------------------------------------------------------------
// stage3 + mask + log_softmax. Block 256 = 4 waves (wave = o).
// grid (6 = xtile*2+b, 3 ytile, Zcur). Direct-streaming fragments (no staging
// LDS, no barriers before epilogue); LDS only for the 4-o epilogue exchange
// (36.9 KB -> 4 blocks/CU).
// VAR0: C[x][y] = sum_i st[x,i] * t1[z,o][y][i]
// VAR1: C[x][y] = sum_i t2[z,o][x][i] * ot[y,i]
// ---------------------------------------------------------------------------
template <int VAR>
__global__ __launch_bounds__(256) void stage3_kernel(
    const u16* __restrict__ tb, const u16* __restrict__ P,
    float* __restrict__ out, int z0, int ZcapT) {
  __shared__ float sf[9216];
  int bx = blockIdx.x;
  int b = bx & 1, xt = (bx >> 1) * 48;
  int yt = blockIdx.y * 48;
  int zl = blockIdx.z;
  int zg = z0 + zl;
  int tid = threadIdx.x;
  const float NL4 = -1.3862943611198906f;
  size_t obase = ((size_t)(b * 144 + zg)) * 82944;
  if (zg > xt + 47) {  // fully masked tile
    float4 v = make_float4(NL4, NL4, NL4, NL4);
    for (int p = tid; p < 2304; p += 256) {
      int xl = p / 48, yl = p - xl * 48;
      *(float4*)(out + obase + ((size_t)(xt + xl) * 144 + yt + yl) * 4) = v;
    }
    return;
  }
  int pbase = (VAR == 0) ? xt : yt;
  int qbase = (VAR == 0) ? yt : xt;
  int lane = tid & 63, o = tid >> 6, l16 = lane & 15, quad = lane >> 4;
  const u16* Pp = P + (size_t)b * 23040 + (size_t)(pbase + l16) * 160 + quad * 8;
  const u16* Tp = tb + (size_t)b * ZcapT + (size_t)zl * 92160 +
                  (size_t)(o * 144 + qbase + l16) * 160 + quad * 8;
  const u16* Ap = (VAR == 0) ? Pp : Tp;  // A side = x rows (both variants)
  const u16* Bp = (VAR == 0) ? Tp : Pp;  // B side = y rows
  f32x4 acc[3][3];
#pragma unroll
  for (int mi = 0; mi < 3; ++mi)
#pragma unroll
    for (int ni = 0; ni < 3; ++ni) acc[mi][ni] = (f32x4){0.f, 0.f, 0.f, 0.f};

#pragma unroll
  for (int ks = 0; ks < 5; ++ks) {
    bf16x8 af[3], bfr[3];
#pragma unroll
    for (int mi = 0; mi < 3; ++mi)
      af[mi] = *(const bf16x8*)(Ap + (size_t)mi * 16 * 160 + ks * 32);
#pragma unroll
    for (int ni = 0; ni < 3; ++ni)
      bfr[ni] = *(const bf16x8*)(Bp + (size_t)ni * 16 * 160 + ks * 32);
#pragma unroll
    for (int mi = 0; mi < 3; ++mi)
#pragma unroll
      for (int ni = 0; ni < 3; ++ni)
        acc[mi][ni] = __builtin_amdgcn_mfma_f32_16x16x32_bf16(
            af[mi], bfr[ni], acc[mi][ni], 0, 0, 0);
  }

#pragma unroll
  for (int mi = 0; mi < 3; ++mi)
#pragma unroll
    for (int ni = 0; ni < 3; ++ni)
#pragma unroll
      for (int r = 0; r < 4; ++r)
        sf[((mi * 16 + quad * 4 + r) * 48 + ni * 16 + l16) * 4 + o] =
            acc[mi][ni][r];
  __syncthreads();
  for (int p = tid; p < 2304; p += 256) {
    int xl = p / 48, yl = p - xl * 48;
    int xg = xt + xl;
    float4 v;
    if (zg > xg) {
      v = make_float4(NL4, NL4, NL4, NL4);
    } else {
      float c0 = sf[p * 4], c1 = sf[p * 4 + 1];
      float c2 = sf[p * 4 + 2], c3 = sf[p * 4 + 3];
      float mx = fmaxf(fmaxf(c0, c1), fmaxf(c2, c3));
      float l = mx + logf(expf(c0 - mx) + expf(c1 - mx) + expf(c2 - mx) +
                          expf(c3 - mx));
      v = make_float4(c0 - l, c1 - l, c2 - l, c3 - l);
    }
    *(float4*)(out + obase + ((size_t)xg * 144 + yt + yl) * 4) = v;
  }
}

// ---------------------------------------------------------------------------
extern "C" void kernel_launch(void* const* d_in, const int* in_sizes, int n_in,
                              void* d_out, int out_size, void* d_ws,
                              size_t ws_size, hipStream_t stream) {
  const float* x = (const float*)d_in[0];
  const float* Wsh = (const float*)d_in[1];
  const float* bsh = (const float*)d_in[2];
  const float* Wst = (const float*)d_in[3];
  const float* bst = (const float*)d_in[4];
  const float* Woh = (const float*)d_in[5];
  const float* boh = (const float*)d_in[6];
  const float* Wot = (const float*)d_in[7];
  const float* bot = (const float*)d_in[8];
  const float* Wt1 = (const float*)d_in[9];
  const float* Wt2 = (const float*)d_in[10];

  u16* ws = (u16*)d_ws;
  u16* xb = ws;                   // 294912
  u16* WT4 = ws + 294912;         // 655360
  u16* pAll = ws + 950272;        // 184320 : [p][288][160]
  u16* WtT = ws + 1134592;        // 15360000
  u16* dyn = ws + 16494592;
  size_t ws_u = ws_size / 2;
  long long avail = (long long)ws_u - 16494592LL;
  int Zc = (avail > 0) ? (int)(avail / 389120) : 1;
  if (Zc > 144) Zc = 144;
  if (Zc < 1) Zc = 1;
  int ZcapW = Zc * 102400, ZcapT = Zc * 92160;
  u16* wbuf = dyn;
  u16* tbuf = dyn + (size_t)2 * ZcapW;

  conv_x<<<288, 256, 0, stream>>>(x, xb);
  trans_wp<<<dim3(16, 4), 256, 0, stream>>>(Wsh, Wst, Woh, Wot, WT4);
  gemm_ds<0><<<dim3(8, 2), 192, 0, stream>>>(xb, WT4, pAll, 288, 0, 0, bsh,
                                             bst, boh, bot);

  float* out0 = (float*)d_out;
  float* out1 = out0 + 23887872;  // 2*144^3*4

  for (int tri = 0; tri < 2; ++tri) {
    transw_kernel<<<dim3(600, 2), 256, 0, stream>>>(tri ? Wt2 : Wt1, WtT);
    const u16* shsec = pAll;                                    // p0 = sh
    const u16* pQ = pAll + (size_t)(tri ? 1 : 2) * 46080;       // st : oh
    const u16* pP = pAll + (size_t)(tri ? 3 : 1) * 46080;       // ot : st
    float* outT = tri ? out1 : out0;
    for (int z0 = 0; z0 < 144; z0 += Zc) {
      int Zcur = (Zc < 144 - z0) ? Zc : (144 - z0);
      gemm_ds<1><<<dim3(2, 600, 2), 192, 0, stream>>>(
          shsec + (size_t)z0 * 160, WtT, wbuf, Zcur, ZcapW, 0, nullptr,
          nullptr, nullptr, nullptr);
      gemm_ds<2><<<dim3(2, Zcur * 4, 2), 192, 0, stream>>>(
          pQ, wbuf, tbuf, 144, ZcapW, ZcapT, nullptr, nullptr, nullptr,
          nullptr);
      dim3 g3(6, 3, Zcur);
      if (tri == 0)
        stage3_kernel<0><<<g3, 256, 0, stream>>>(tbuf, pP, outT, z0, ZcapT);
      else
        stage3_kernel<1><<<g3, 256, 0, stream>>>(tbuf, pP, outT, z0, ZcapT);
    }
  }
}